// Round 1
// baseline (272.864 us; speedup 1.0000x reference)
//
#include <hip/hip_runtime.h>
#include <hip/hip_bf16.h>
#include <cstdint>
#include <cstddef>

typedef __bf16 bf16x8 __attribute__((ext_vector_type(8)));
typedef float f32x4 __attribute__((ext_vector_type(4)));
typedef unsigned int uintx4 __attribute__((ext_vector_type(4)));

#define CONV_SCALE 0.014731391274719738f   // 1/sqrt(512*9)
#define MOD_SCALE  0.044194173824159216f   // 1/sqrt(512)

__device__ __forceinline__ unsigned short f2bf(float v) {
  unsigned int u = __float_as_uint(v);
  return (unsigned short)((u + 0x7FFFu + ((u >> 16) & 1u)) >> 16);  // RNE
}

// s[b][ci] = dot(style[b], mod_w[ci]) * MOD_SCALE + mod_b[ci]
__global__ void k_modulate(const float* __restrict__ style,
                           const float* __restrict__ mod_w,
                           const float* __restrict__ mod_b,
                           float* __restrict__ s) {
  int b = blockIdx.x;        // 8
  int ci = threadIdx.x;      // 512
  const float* st = style + b * 512;
  const float* mw = mod_w + (size_t)ci * 512;
  float acc = 0.f;
  #pragma unroll 8
  for (int k = 0; k < 512; ++k) acc += st[k] * mw[k];
  s[b * 512 + ci] = acc * MOD_SCALE + mod_b[ci];
}

// wsq[co][ci] = conv_scale^2 * sum_tap weight[co][ci][tap]^2
__global__ void k_wsq(const float* __restrict__ weight, float* __restrict__ wsq) {
  int idx = blockIdx.x * 256 + threadIdx.x;   // 262144 total
  const float* w = weight + (size_t)idx * 9;
  float acc = 0.f;
  #pragma unroll
  for (int k = 0; k < 9; ++k) { float v = w[k]; acc += v * v; }
  wsq[idx] = acc * (CONV_SCALE * CONV_SCALE);
}

// demod[b][co] = rsqrt( sum_ci wsq[co][ci]*s[b][ci]^2 + 1e-8 )
__global__ void k_demod(const float* __restrict__ wsq, const float* __restrict__ s,
                        float* __restrict__ demod) {
  int b = blockIdx.x;        // 8
  int co = threadIdx.x;      // 512
  const float* wq = wsq + (size_t)co * 512;
  const float* sb = s + b * 512;
  float acc = 0.f;
  #pragma unroll 8
  for (int ci = 0; ci < 512; ++ci) { float sv = sb[ci]; acc += wq[ci] * sv * sv; }
  demod[b * 512 + co] = rsqrtf(acc + 1e-8f);
}

// xT[b][h][w][ci] = bf16( x[b][ci][h][w] * s[b][ci] )   (transpose to ci-contiguous)
__global__ void k_xT(const float* __restrict__ x, const float* __restrict__ s,
                     unsigned short* __restrict__ xT) {
  __shared__ float lds[64][65];
  int cc = blockIdx.x;       // ci chunk of 64 (8 chunks)
  int h = blockIdx.y;        // 64
  int b = blockIdx.z;        // 8
  int t = threadIdx.x;       // 256
  int w = t & 63, r4 = t >> 6;
  #pragma unroll
  for (int i = 0; i < 16; ++i) {
    int ci = i * 4 + r4;
    lds[ci][w] = x[(((size_t)(b * 512 + cc * 64 + ci)) * 64 + h) * 64 + w];
  }
  __syncthreads();
  int pos = t >> 2, c4 = t & 3;
  #pragma unroll
  for (int half = 0; half < 2; ++half) {
    int cb = half * 32 + c4 * 8;
    union { uintx4 v; unsigned short us[8]; } pk;
    #pragma unroll
    for (int j = 0; j < 8; ++j) {
      int ci = cb + j;
      pk.us[j] = f2bf(lds[ci][pos] * s[b * 512 + cc * 64 + ci]);
    }
    *(uintx4*)(xT + (((size_t)(b * 64 + h)) * 64 + pos) * 512 + cc * 64 + cb) = pk.v;
  }
}

// wT[tap][co][ci] = bf16( weight[co][ci][tap] )   (tap-major, ci-contiguous; no scales)
__global__ void k_wT(const float* __restrict__ weight, unsigned short* __restrict__ wT) {
  __shared__ float lds[4608];
  int co = blockIdx.x;       // 512
  int t = threadIdx.x;       // 256
  const float* w = weight + (size_t)co * 4608;
  #pragma unroll
  for (int i = 0; i < 18; ++i) lds[t + i * 256] = w[t + i * 256];
  __syncthreads();
  for (int i = t; i < 576; i += 256) {
    int tap = i / 64, c8 = (i & 63) * 8;
    union { uintx4 v; unsigned short us[8]; } pk;
    #pragma unroll
    for (int j = 0; j < 8; ++j) pk.us[j] = f2bf(lds[(c8 + j) * 9 + tap]);
    *(uintx4*)(wT + ((size_t)tap * 512 + co) * 512 + c8) = pk.v;
  }
}

// Implicit-GEMM conv. Block tile: 64 Cout x (4 rows x 64 cols), 4 waves (one output row each).
// K-loop: 16 chunks of 32 ci, inner 9 taps. MFMA 16x16x32 bf16.
// LDS rows are 64B (32 ci bf16), XOR-swizzled 16B slots: slot ^= (row>>1)&3  -> <=2-way banks.
__global__ __launch_bounds__(256, 2) void k_conv(
    const unsigned short* __restrict__ xT,   // [B][64][64][512]
    const unsigned short* __restrict__ wT,   // [9][512][512]
    const float* __restrict__ demod,         // [B][512]
    float* __restrict__ out) {               // [B][512][64][64]
  __shared__ __align__(16) char lds_raw[62208];
  char* xlds = lds_raw;           // 396 rows (6*66 halo positions) * 64B = 25344
  char* wlds = lds_raw + 25344;   // 576 rows (9 taps * 64 co)      * 64B = 36864

  const int co_t = blockIdx.x;    // 8
  const int h_t  = blockIdx.y;    // 16
  const int b    = blockIdx.z;    // 8
  const int t = threadIdx.x;
  const int lane = t & 63, wv = t >> 6;
  const int h0 = h_t * 4;
  const int co0 = co_t * 64;
  const int l15 = lane & 15, kg = lane >> 4;

  f32x4 acc[4][4] = {};           // [m(co)][n(w)]

  for (int cc = 0; cc < 16; ++cc) {
    __syncthreads();
    // stage x halo tile: p = r*66 + wc ; input (h0-1+r, wc-1), zero-padded borders
    for (int i = t; i < 1584; i += 256) {      // 396 positions * 4 slots
      int p = i >> 2, slot = i & 3;
      int r = p / 66, wc = p - r * 66;
      int hh = h0 - 1 + r, wwc = wc - 1;
      uintx4 v = {0u, 0u, 0u, 0u};
      if ((unsigned)hh < 64u && (unsigned)wwc < 64u)
        v = *(const uintx4*)(xT + (((size_t)(b * 64 + hh)) * 64 + wwc) * 512 + cc * 32 + slot * 8);
      *(uintx4*)(xlds + p * 64 + ((slot ^ ((p >> 1) & 3)) << 4)) = v;
    }
    // stage weight tile: row = tap*64 + co
    for (int i = t; i < 2304; i += 256) {      // 576 rows * 4 slots
      int row = i >> 2, slot = i & 3;
      int tap = row >> 6, co = row & 63;
      uintx4 v = *(const uintx4*)(wT + (((size_t)tap * 512) + co0 + co) * 512 + cc * 32 + slot * 8);
      *(uintx4*)(wlds + row * 64 + ((slot ^ ((row >> 1) & 3)) << 4)) = v;
    }
    __syncthreads();

    #pragma unroll
    for (int tap = 0; tap < 9; ++tap) {
      const int dh = tap / 3, dw = tap % 3;
      bf16x8 af[4], bfr[4];
      #pragma unroll
      for (int m = 0; m < 4; ++m) {
        int row = tap * 64 + m * 16 + l15;
        af[m] = *(const bf16x8*)(wlds + row * 64 + ((kg ^ ((row >> 1) & 3)) << 4));
      }
      #pragma unroll
      for (int n = 0; n < 4; ++n) {
        int p = (wv + dh) * 66 + n * 16 + l15 + dw;
        bfr[n] = *(const bf16x8*)(xlds + p * 64 + ((kg ^ ((p >> 1) & 3)) << 4));
      }
      #pragma unroll
      for (int m = 0; m < 4; ++m)
        #pragma unroll
        for (int n = 0; n < 4; ++n)
          acc[m][n] = __builtin_amdgcn_mfma_f32_16x16x32_bf16(af[m], bfr[n], acc[m][n], 0, 0, 0);
    }
  }

  // epilogue: out[b][co][h0+wv][w] = acc * conv_scale * demod[b][co]
  const int h_out = h0 + wv;
  #pragma unroll
  for (int m = 0; m < 4; ++m) {
    #pragma unroll
    for (int r = 0; r < 4; ++r) {
      int co = co0 + m * 16 + kg * 4 + r;
      float scl = CONV_SCALE * demod[b * 512 + co];
      #pragma unroll
      for (int n = 0; n < 4; ++n) {
        out[(((size_t)(b * 512 + co)) * 64 + h_out) * 64 + n * 16 + l15] = acc[m][n][r] * scl;
      }
    }
  }
}

extern "C" void kernel_launch(void* const* d_in, const int* in_sizes, int n_in,
                              void* d_out, int out_size, void* d_ws, size_t ws_size,
                              hipStream_t stream) {
  const float* x      = (const float*)d_in[0];  // (8,512,64,64)
  const float* style  = (const float*)d_in[1];  // (8,512)
  const float* weight = (const float*)d_in[2];  // (1,512,512,3,3)
  const float* mod_w  = (const float*)d_in[3];  // (512,512)
  const float* mod_b  = (const float*)d_in[4];  // (512,)
  float* out = (float*)d_out;

  // workspace layout (needs ~39.4 MB)
  char* ws = (char*)d_ws;
  unsigned short* xT = (unsigned short*)ws;               // 33,554,432 B
  unsigned short* wT = (unsigned short*)(ws + 33554432);  //  4,718,592 B
  float* s     = (float*)(ws + 38273024);                 //     16,384 B
  float* wsq   = (float*)(ws + 38289408);                 //  1,048,576 B
  float* demod = (float*)(ws + 39337984);                 //     16,384 B

  hipLaunchKernelGGL(k_modulate, dim3(8),        dim3(512), 0, stream, style, mod_w, mod_b, s);
  hipLaunchKernelGGL(k_wsq,      dim3(1024),     dim3(256), 0, stream, weight, wsq);
  hipLaunchKernelGGL(k_demod,    dim3(8),        dim3(512), 0, stream, wsq, s, demod);
  hipLaunchKernelGGL(k_xT,       dim3(8, 64, 8), dim3(256), 0, stream, x, s, xT);
  hipLaunchKernelGGL(k_wT,       dim3(512),      dim3(256), 0, stream, weight, wT);
  hipLaunchKernelGGL(k_conv,     dim3(8, 16, 8), dim3(256), 0, stream, xT, wT, demod, out);
}

// Round 2
// 201.512 us; speedup vs baseline: 1.3541x; 1.3541x over previous
//
#include <hip/hip_runtime.h>
#include <hip/hip_bf16.h>
#include <cstdint>
#include <cstddef>

typedef __bf16 bf16x8 __attribute__((ext_vector_type(8)));
typedef float f32x4 __attribute__((ext_vector_type(4)));
typedef unsigned int uintx4 __attribute__((ext_vector_type(4)));

#define CONV_SCALE 0.014731391274719738f   // 1/sqrt(512*9)
#define MOD_SCALE  0.044194173824159216f   // 1/sqrt(512)

__device__ __forceinline__ unsigned short f2bf(float v) {
  unsigned int u = __float_as_uint(v);
  return (unsigned short)((u + 0x7FFFu + ((u >> 16) & 1u)) >> 16);  // RNE
}

__device__ __forceinline__ void gload16(const void* g, void* l) {
  __builtin_amdgcn_global_load_lds(
      (const __attribute__((address_space(1))) unsigned int*)g,
      (__attribute__((address_space(3))) unsigned int*)l, 16, 0, 0);
}

// s[b][ci] = dot(style[b], mod_w[ci]) * MOD_SCALE + mod_b[ci]
// 32 blocks: (b, ci-chunk of 128); 2 threads per ci, halves reduced via shfl.
__global__ void k_modulate(const float* __restrict__ style,
                           const float* __restrict__ mod_w,
                           const float* __restrict__ mod_b,
                           float* __restrict__ s) {
  int blk = blockIdx.x;            // 32
  int b = blk >> 2, ch = blk & 3;
  int t = threadIdx.x;             // 256
  int ci = ch * 128 + (t >> 1), half = t & 1;
  const float* st = style + b * 512 + half * 256;
  const float* mw = mod_w + (size_t)ci * 512 + half * 256;
  float acc = 0.f;
  #pragma unroll 8
  for (int k = 0; k < 256; k += 4) {
    f32x4 a = *(const f32x4*)(st + k);
    f32x4 m = *(const f32x4*)(mw + k);
    acc += a[0] * m[0] + a[1] * m[1] + a[2] * m[2] + a[3] * m[3];
  }
  acc += __shfl_xor(acc, 1);
  if (half == 0) s[b * 512 + ci] = acc * MOD_SCALE + mod_b[ci];
}

// wT[tap][co][ci] = bf16(weight[co][ci][tap]);  wsq[co][ci] = cs^2 * sum_tap w^2
__global__ void k_wTq(const float* __restrict__ weight,
                      unsigned short* __restrict__ wT,
                      float* __restrict__ wsq) {
  __shared__ float lds[4608];
  int co = blockIdx.x;       // 512
  int t = threadIdx.x;       // 256
  const float* w = weight + (size_t)co * 4608;
  #pragma unroll
  for (int i = 0; i < 18; ++i) lds[t + i * 256] = w[t + i * 256];
  __syncthreads();
  for (int i = t; i < 576; i += 256) {
    int tap = i / 64, c8 = (i & 63) * 8;
    union { uintx4 v; unsigned short us[8]; } pk;
    #pragma unroll
    for (int j = 0; j < 8; ++j) pk.us[j] = f2bf(lds[(c8 + j) * 9 + tap]);
    *(uintx4*)(wT + ((size_t)tap * 512 + co) * 512 + c8) = pk.v;
  }
  for (int ci = t; ci < 512; ci += 256) {
    float a = 0.f;
    #pragma unroll
    for (int tap = 0; tap < 9; ++tap) { float v = lds[ci * 9 + tap]; a += v * v; }
    wsq[co * 512 + ci] = a * (CONV_SCALE * CONV_SCALE);
  }
}

// demod[b][co] = rsqrt( sum_ci wsq[co][ci]*s[b][ci]^2 + 1e-8 )
__global__ void k_demod(const float* __restrict__ wsq, const float* __restrict__ s,
                        float* __restrict__ demod) {
  int b = blockIdx.x;        // 8
  int co = threadIdx.x;      // 512
  const float* wq = wsq + (size_t)co * 512;
  const float* sb = s + b * 512;
  float acc = 0.f;
  #pragma unroll 4
  for (int ci = 0; ci < 512; ci += 4) {
    f32x4 q = *(const f32x4*)(wq + ci);
    f32x4 v = *(const f32x4*)(sb + ci);
    acc += q[0] * v[0] * v[0] + q[1] * v[1] * v[1] + q[2] * v[2] * v[2] + q[3] * v[3] * v[3];
  }
  demod[b * 512 + co] = rsqrtf(acc + 1e-8f);
}

// xT[b][h][w][ci] = bf16( x[b][ci][h][w] * s[b][ci] )   (transpose to ci-contiguous)
__global__ void k_xT(const float* __restrict__ x, const float* __restrict__ s,
                     unsigned short* __restrict__ xT) {
  __shared__ float lds[128][68];   // pad 68 -> 16B-aligned float4 rows, bank-spread cols
  int cc = blockIdx.x;       // ci chunk of 128 (4 chunks)
  int h = blockIdx.y;        // 64
  int b = blockIdx.z;        // 8
  int t = threadIdx.x;       // 256
  int w4 = (t & 15) * 4, rr = t >> 4;
  #pragma unroll
  for (int i = 0; i < 8; ++i) {
    int ci = i * 16 + rr;
    *(f32x4*)&lds[ci][w4] =
        *(const f32x4*)&x[(((size_t)(b * 512 + cc * 128 + ci)) * 64 + h) * 64 + w4];
  }
  __syncthreads();
  int pos = t >> 2, c4 = t & 3;
  #pragma unroll
  for (int q = 0; q < 4; ++q) {
    int cb = q * 32 + c4 * 8;
    union { uintx4 v; unsigned short us[8]; } pk;
    #pragma unroll
    for (int j = 0; j < 8; ++j) {
      int ci = cb + j;
      pk.us[j] = f2bf(lds[ci][pos] * s[b * 512 + cc * 128 + ci]);
    }
    *(uintx4*)(xT + (((size_t)(b * 64 + h)) * 64 + pos) * 512 + cc * 128 + cb) = pk.v;
  }
}

// Implicit-GEMM conv. Block tile: 64 Cout x (4 rows x 64 cols), 4 waves.
// K-loop: 16 chunks of 32 ci, inner 9 taps. MFMA 16x16x32 bf16.
// Staging via global_load_lds_dwordx4: linear LDS dest, PRE-SWIZZLED global source
// (slot' = slot ^ ((row>>1)&3)); read path applies the same XOR -> <=2-way banks.
// Halo borders (wc=0,65) and OOB h-rows are zero-filled ONCE before the K-loop
// and never re-staged.
__global__ __launch_bounds__(256, 2) void k_conv(
    const unsigned short* __restrict__ xT,   // [B][64][64][512]
    const unsigned short* __restrict__ wT,   // [9][512][512]
    const float* __restrict__ demod,         // [B][512]
    float* __restrict__ out) {               // [B][512][64][64]
  __shared__ __align__(16) char lds_raw[62208];
  char* xlds = lds_raw;           // 396 positions (6*66) * 64B = 25344
  char* wlds = lds_raw + 25344;   // 576 rows (9 taps * 64 co) * 64B = 36864

  const int co_t = blockIdx.x;    // 8
  const int h_t  = blockIdx.y;    // 16
  const int b    = blockIdx.z;    // 8
  const int t = threadIdx.x;
  const int lane = t & 63, wv = t >> 6;
  const int h0 = h_t * 4;
  const int co0 = co_t * 64;
  const int l15 = lane & 15, kg = lane >> 4;

  // zero whole x tile once (covers halo cols 0/65 and OOB rows forever)
  {
    uintx4 z = {0u, 0u, 0u, 0u};
    for (int i = t; i < 1584; i += 256) ((uintx4*)xlds)[i] = z;
  }

  f32x4 acc[4][4] = {};           // [m(co)][n(w)]

  for (int cc = 0; cc < 16; ++cc) {
    __syncthreads();
    // stage x interior: 6 rows x 4 chunks of 16 positions (1KB per issue)
    for (int j = wv; j < 24; j += 4) {
      int r = j >> 2, k = j & 3;
      int hh = h0 - 1 + r;
      if ((unsigned)hh < 64u) {
        int p = r * 66 + 1 + k * 16 + (lane >> 2);
        const unsigned short* g = xT + (((size_t)(b * 64 + hh)) * 64 + k * 16 + (lane >> 2)) * 512
                                  + cc * 32 + (((lane & 3) ^ ((p >> 1) & 3)) << 3);
        gload16(g, xlds + (r * 66 + 1 + k * 16) * 64);
      }
    }
    // stage weights: 36 chunks of 16 rows
    for (int j = wv; j < 36; j += 4) {
      int row0 = j * 16;
      int row = row0 + (lane >> 2);
      int tap = row >> 6, co = row & 63;
      const unsigned short* g = wT + ((size_t)tap * 512 + co0 + co) * 512
                                + cc * 32 + (((lane & 3) ^ ((row >> 1) & 3)) << 3);
      gload16(g, wlds + row0 * 64);
    }
    __syncthreads();

    #pragma unroll
    for (int tap = 0; tap < 9; ++tap) {
      const int dh = tap / 3, dw = tap % 3;
      bf16x8 af[4], bfr[4];
      #pragma unroll
      for (int m = 0; m < 4; ++m) {
        int row = tap * 64 + m * 16 + l15;
        af[m] = *(const bf16x8*)(wlds + row * 64 + ((kg ^ ((row >> 1) & 3)) << 4));
      }
      #pragma unroll
      for (int n = 0; n < 4; ++n) {
        int p = (wv + dh) * 66 + n * 16 + l15 + dw;
        bfr[n] = *(const bf16x8*)(xlds + p * 64 + ((kg ^ ((p >> 1) & 3)) << 4));
      }
      #pragma unroll
      for (int m = 0; m < 4; ++m)
        #pragma unroll
        for (int n = 0; n < 4; ++n)
          acc[m][n] = __builtin_amdgcn_mfma_f32_16x16x32_bf16(af[m], bfr[n], acc[m][n], 0, 0, 0);
    }
  }

  // epilogue: out[b][co][h0+wv][w] = acc * conv_scale * demod[b][co]
  const int h_out = h0 + wv;
  #pragma unroll
  for (int m = 0; m < 4; ++m) {
    #pragma unroll
    for (int r = 0; r < 4; ++r) {
      int co = co0 + m * 16 + kg * 4 + r;
      float scl = CONV_SCALE * demod[b * 512 + co];
      #pragma unroll
      for (int n = 0; n < 4; ++n) {
        out[(((size_t)(b * 512 + co)) * 64 + h_out) * 64 + n * 16 + l15] = acc[m][n][r] * scl;
      }
    }
  }
}

extern "C" void kernel_launch(void* const* d_in, const int* in_sizes, int n_in,
                              void* d_out, int out_size, void* d_ws, size_t ws_size,
                              hipStream_t stream) {
  const float* x      = (const float*)d_in[0];  // (8,512,64,64)
  const float* style  = (const float*)d_in[1];  // (8,512)
  const float* weight = (const float*)d_in[2];  // (1,512,512,3,3)
  const float* mod_w  = (const float*)d_in[3];  // (512,512)
  const float* mod_b  = (const float*)d_in[4];  // (512,)
  float* out = (float*)d_out;

  // workspace layout (~39.4 MB)
  char* ws = (char*)d_ws;
  unsigned short* xT = (unsigned short*)ws;               // 33,554,432 B
  unsigned short* wT = (unsigned short*)(ws + 33554432);  //  4,718,592 B
  float* s     = (float*)(ws + 38273024);                 //     16,384 B
  float* wsq   = (float*)(ws + 38289408);                 //  1,048,576 B
  float* demod = (float*)(ws + 39337984);                 //     16,384 B

  hipLaunchKernelGGL(k_modulate, dim3(32),       dim3(256), 0, stream, style, mod_w, mod_b, s);
  hipLaunchKernelGGL(k_wTq,      dim3(512),      dim3(256), 0, stream, weight, wT, wsq);
  hipLaunchKernelGGL(k_demod,    dim3(8),        dim3(512), 0, stream, wsq, s, demod);
  hipLaunchKernelGGL(k_xT,       dim3(4, 64, 8), dim3(256), 0, stream, x, s, xT);
  hipLaunchKernelGGL(k_conv,     dim3(8, 16, 8), dim3(256), 0, stream, xT, wT, demod, out);
}

// Round 3
// 193.879 us; speedup vs baseline: 1.4074x; 1.0394x over previous
//
#include <hip/hip_runtime.h>
#include <hip/hip_bf16.h>
#include <cstdint>
#include <cstddef>

typedef __bf16 bf16x8 __attribute__((ext_vector_type(8)));
typedef float f32x4 __attribute__((ext_vector_type(4)));
typedef unsigned int uintx4 __attribute__((ext_vector_type(4)));

#define CONV_SCALE 0.014731391274719738f   // 1/sqrt(512*9)
#define MOD_SCALE  0.044194173824159216f   // 1/sqrt(512)

__device__ __forceinline__ unsigned short f2bf(float v) {
  unsigned int u = __float_as_uint(v);
  return (unsigned short)((u + 0x7FFFu + ((u >> 16) & 1u)) >> 16);  // RNE
}

__device__ __forceinline__ void gload16(const void* g, void* l) {
  __builtin_amdgcn_global_load_lds(
      (const __attribute__((address_space(1))) unsigned int*)g,
      (__attribute__((address_space(3))) unsigned int*)l, 16, 0, 0);
}

// s[b][ci] = dot(style[b], mod_w[ci]) * MOD_SCALE + mod_b[ci]
__global__ void k_modulate(const float* __restrict__ style,
                           const float* __restrict__ mod_w,
                           const float* __restrict__ mod_b,
                           float* __restrict__ s) {
  int blk = blockIdx.x;            // 32
  int b = blk >> 2, ch = blk & 3;
  int t = threadIdx.x;             // 256
  int ci = ch * 128 + (t >> 1), half = t & 1;
  const float* st = style + b * 512 + half * 256;
  const float* mw = mod_w + (size_t)ci * 512 + half * 256;
  float acc = 0.f;
  #pragma unroll 8
  for (int k = 0; k < 256; k += 4) {
    f32x4 a = *(const f32x4*)(st + k);
    f32x4 m = *(const f32x4*)(mw + k);
    acc += a[0] * m[0] + a[1] * m[1] + a[2] * m[2] + a[3] * m[3];
  }
  acc += __shfl_xor(acc, 1);
  if (half == 0) s[b * 512 + ci] = acc * MOD_SCALE + mod_b[ci];
}

// wT[tap][co][ci] = bf16(weight[co][ci][tap]);  wsq[co][ci] = cs^2 * sum_tap w^2
__global__ void k_wTq(const float* __restrict__ weight,
                      unsigned short* __restrict__ wT,
                      float* __restrict__ wsq) {
  __shared__ float lds[4608];
  int co = blockIdx.x;       // 512
  int t = threadIdx.x;       // 256
  const float* w = weight + (size_t)co * 4608;
  #pragma unroll
  for (int i = 0; i < 18; ++i) lds[t + i * 256] = w[t + i * 256];
  __syncthreads();
  for (int i = t; i < 576; i += 256) {
    int tap = i / 64, c8 = (i & 63) * 8;
    union { uintx4 v; unsigned short us[8]; } pk;
    #pragma unroll
    for (int j = 0; j < 8; ++j) pk.us[j] = f2bf(lds[(c8 + j) * 9 + tap]);
    *(uintx4*)(wT + ((size_t)tap * 512 + co) * 512 + c8) = pk.v;
  }
  for (int ci = t; ci < 512; ci += 256) {
    float a = 0.f;
    #pragma unroll
    for (int tap = 0; tap < 9; ++tap) { float v = lds[ci * 9 + tap]; a += v * v; }
    wsq[co * 512 + ci] = a * (CONV_SCALE * CONV_SCALE);
  }
}

// demod[b][co] = rsqrt( sum_ci wsq[co][ci]*s[b][ci]^2 + 1e-8 )
__global__ void k_demod(const float* __restrict__ wsq, const float* __restrict__ s,
                        float* __restrict__ demod) {
  int b = blockIdx.x;        // 8
  int co = threadIdx.x;      // 512
  const float* wq = wsq + (size_t)co * 512;
  const float* sb = s + b * 512;
  float acc = 0.f;
  #pragma unroll 4
  for (int ci = 0; ci < 512; ci += 4) {
    f32x4 q = *(const f32x4*)(wq + ci);
    f32x4 v = *(const f32x4*)(sb + ci);
    acc += q[0] * v[0] * v[0] + q[1] * v[1] * v[1] + q[2] * v[2] * v[2] + q[3] * v[3] * v[3];
  }
  demod[b * 512 + co] = rsqrtf(acc + 1e-8f);
}

// xT[b][h][w][ci] = bf16( x[b][ci][h][w] * s[b][ci] )   (transpose to ci-contiguous)
__global__ void k_xT(const float* __restrict__ x, const float* __restrict__ s,
                     unsigned short* __restrict__ xT) {
  __shared__ float lds[128][68];
  int cc = blockIdx.x;       // ci chunk of 128 (4 chunks)
  int h = blockIdx.y;        // 64
  int b = blockIdx.z;        // 8
  int t = threadIdx.x;       // 256
  int w4 = (t & 15) * 4, rr = t >> 4;
  #pragma unroll
  for (int i = 0; i < 8; ++i) {
    int ci = i * 16 + rr;
    *(f32x4*)&lds[ci][w4] =
        *(const f32x4*)&x[(((size_t)(b * 512 + cc * 128 + ci)) * 64 + h) * 64 + w4];
  }
  __syncthreads();
  int pos = t >> 2, c4 = t & 3;
  #pragma unroll
  for (int q = 0; q < 4; ++q) {
    int cb = q * 32 + c4 * 8;
    union { uintx4 v; unsigned short us[8]; } pk;
    #pragma unroll
    for (int j = 0; j < 8; ++j) {
      int ci = cb + j;
      pk.us[j] = f2bf(lds[ci][pos] * s[b * 512 + cc * 128 + ci]);
    }
    *(uintx4*)(xT + (((size_t)(b * 64 + h)) * 64 + pos) * 512 + cc * 128 + cb) = pk.v;
  }
}

// Implicit-GEMM conv. Block tile: 64 Cout x (8 rows x 64 cols), 4 waves (2 rows each).
// K-loop: 16 chunks of 32 ci, inner 9 taps. MFMA 16x16x32 bf16.
// Per tap per wave: 4 af + 8 bfr ds_read_b128 -> 32 MFMA (weight reuse 8).
// Staging via global_load_lds_dwordx4: linear LDS dest, PRE-SWIZZLED global source
// (slot' = slot ^ ((row>>1)&3)); reads apply same XOR -> conflict-free.
// LDS: x halo 10 rows x 66 pos x 64B = 42240 + weights 576 x 64B = 36864 -> 79104 B dynamic.
__global__ __launch_bounds__(256, 2) void k_conv(
    const unsigned short* __restrict__ xT,   // [B][64][64][512]
    const unsigned short* __restrict__ wT,   // [9][512][512]
    const float* __restrict__ demod,         // [B][512]
    float* __restrict__ out) {               // [B][512][64][64]
  extern __shared__ __align__(16) char lds_raw[];
  char* xlds = lds_raw;            // 660 positions (10*66) * 64B = 42240
  char* wlds = lds_raw + 42240;    // 576 rows (9 taps * 64 co) * 64B = 36864

  const int co_t = blockIdx.x;    // 8
  const int h_t  = blockIdx.y;    // 8
  const int b    = blockIdx.z;    // 8
  const int t = threadIdx.x;
  const int lane = t & 63, wv = t >> 6;
  const int h0 = h_t * 8;
  const int co0 = co_t * 64;
  const int l15 = lane & 15, kg = lane >> 4;

  // zero whole x tile once (covers halo cols 0/65 and OOB rows forever)
  {
    uintx4 z = {0u, 0u, 0u, 0u};
    for (int i = t; i < 2640; i += 256) ((uintx4*)xlds)[i] = z;
  }

  f32x4 acc[4][2][4] = {};        // [m(co)][r(row)][n(w)]

  for (int cc = 0; cc < 16; ++cc) {
    __syncthreads();
    // stage x interior: 10 rows x 4 chunks of 16 positions (1KB per issue)
    for (int j = wv; j < 40; j += 4) {
      int r = j >> 2, k = j & 3;
      int hh = h0 - 1 + r;
      if ((unsigned)hh < 64u) {
        int p0 = r * 66 + 1 + k * 16;
        int p = p0 + (lane >> 2);
        const unsigned short* g = xT + (((size_t)(b * 64 + hh)) * 64 + k * 16 + (lane >> 2)) * 512
                                  + cc * 32 + (((lane & 3) ^ ((p >> 1) & 3)) << 3);
        gload16(g, xlds + p0 * 64);
      }
    }
    // stage weights: 36 chunks of 16 rows
    for (int j = wv; j < 36; j += 4) {
      int row0 = j * 16;
      int row = row0 + (lane >> 2);
      int tap = row >> 6, co = row & 63;
      const unsigned short* g = wT + ((size_t)tap * 512 + co0 + co) * 512
                                + cc * 32 + (((lane & 3) ^ ((row >> 1) & 3)) << 3);
      gload16(g, wlds + row0 * 64);
    }
    __syncthreads();

    #pragma unroll
    for (int tap = 0; tap < 9; ++tap) {
      const int dh = tap / 3, dw = tap % 3;
      bf16x8 af[4], bfr[2][4];
      #pragma unroll
      for (int m = 0; m < 4; ++m) {
        int row = tap * 64 + m * 16 + l15;
        af[m] = *(const bf16x8*)(wlds + row * 64 + ((kg ^ ((row >> 1) & 3)) << 4));
      }
      #pragma unroll
      for (int r = 0; r < 2; ++r)
        #pragma unroll
        for (int n = 0; n < 4; ++n) {
          int p = (2 * wv + r + dh) * 66 + n * 16 + l15 + dw;
          bfr[r][n] = *(const bf16x8*)(xlds + p * 64 + ((kg ^ ((p >> 1) & 3)) << 4));
        }
      #pragma unroll
      for (int m = 0; m < 4; ++m)
        #pragma unroll
        for (int r = 0; r < 2; ++r)
          #pragma unroll
          for (int n = 0; n < 4; ++n)
            acc[m][r][n] = __builtin_amdgcn_mfma_f32_16x16x32_bf16(af[m], bfr[r][n], acc[m][r][n], 0, 0, 0);
    }
  }

  // epilogue: out[b][co][h0+2*wv+r][w] = acc * conv_scale * demod[b][co]
  #pragma unroll
  for (int m = 0; m < 4; ++m) {
    #pragma unroll
    for (int q = 0; q < 4; ++q) {
      int co = co0 + m * 16 + kg * 4 + q;
      float scl = CONV_SCALE * demod[b * 512 + co];
      #pragma unroll
      for (int r = 0; r < 2; ++r) {
        int h_out = h0 + 2 * wv + r;
        #pragma unroll
        for (int n = 0; n < 4; ++n) {
          out[(((size_t)(b * 512 + co)) * 64 + h_out) * 64 + n * 16 + l15] = acc[m][r][n][q] * scl;
        }
      }
    }
  }
}

extern "C" void kernel_launch(void* const* d_in, const int* in_sizes, int n_in,
                              void* d_out, int out_size, void* d_ws, size_t ws_size,
                              hipStream_t stream) {
  const float* x      = (const float*)d_in[0];  // (8,512,64,64)
  const float* style  = (const float*)d_in[1];  // (8,512)
  const float* weight = (const float*)d_in[2];  // (1,512,512,3,3)
  const float* mod_w  = (const float*)d_in[3];  // (512,512)
  const float* mod_b  = (const float*)d_in[4];  // (512,)
  float* out = (float*)d_out;

  // workspace layout (~39.4 MB)
  char* ws = (char*)d_ws;
  unsigned short* xT = (unsigned short*)ws;               // 33,554,432 B
  unsigned short* wT = (unsigned short*)(ws + 33554432);  //  4,718,592 B
  float* s     = (float*)(ws + 38273024);                 //     16,384 B
  float* wsq   = (float*)(ws + 38289408);                 //  1,048,576 B
  float* demod = (float*)(ws + 39337984);                 //     16,384 B

  // allow 79104 B dynamic LDS (no-op if already allowed)
  static int lds_set = 0;
  if (!lds_set) {
    (void)hipFuncSetAttribute((const void*)k_conv,
                              hipFuncAttributeMaxDynamicSharedMemorySize, 79104);
    lds_set = 1;
  }

  hipLaunchKernelGGL(k_modulate, dim3(32),       dim3(256), 0, stream, style, mod_w, mod_b, s);
  hipLaunchKernelGGL(k_wTq,      dim3(512),      dim3(256), 0, stream, weight, wT, wsq);
  hipLaunchKernelGGL(k_demod,    dim3(8),        dim3(512), 0, stream, wsq, s, demod);
  hipLaunchKernelGGL(k_xT,       dim3(4, 64, 8), dim3(256), 0, stream, x, s, xT);
  hipLaunchKernelGGL(k_conv,     dim3(8, 8, 8),  dim3(256), 79104, stream, xT, wT, demod, out);
}